// Round 8
// baseline (1062.234 us; speedup 1.0000x reference)
//
#include <hip/hip_runtime.h>

// Problem constants (from reference)
#define BATCH 2048
#define T 512
#define NF 10
#define HID 30
#define S3T 1536          // 3*T sequence length after reshape/transpose
#define FEAT_PER_B 15360  // T*30 floats per batch element
// Workspace: BATCH * FEAT_PER_B * 4 = 125,829,120 bytes (fp32 feat)

typedef float v2f __attribute__((ext_vector_type(2)));  // -> v_pk_fma_f32

__device__ __forceinline__ float fexp(float x) {
    return __builtin_amdgcn_exp2f(x * 1.44269504088896f);  // v_exp_f32
}
__device__ __forceinline__ float frcp(float x) {
    return __builtin_amdgcn_rcpf(x);                        // v_rcp_f32
}
__device__ __forceinline__ float sigmoid_(float x) {
    return frcp(1.0f + fexp(-x));
}
__device__ __forceinline__ float tanh_(float x) {
    return 2.0f * frcp(1.0f + fexp(-2.0f * x)) - 1.0f;
}

// Kernel 1: materialize featflat[b][t*30+c] = concat(e_i, e_j, rbf)
__global__ void feat_kernel(const int* __restrict__ atom_i,
                            const int* __restrict__ atom_j,
                            const float* __restrict__ dist,
                            const float* __restrict__ emb,
                            float* __restrict__ feat) {
    int gid = blockIdx.x * blockDim.x + threadIdx.x;
    const int total = BATCH * FEAT_PER_B;
    if (gid >= total) return;
    int b = gid / FEAT_PER_B;
    int r = gid - b * FEAT_PER_B;
    int t = r / 30;
    int c = r - t * 30;
    int bt = b * T + t;
    float v;
    if (c < 10) {
        int ai = atom_i[bt];
        v = (ai != 0) ? emb[ai * NF + c] : 0.0f;
    } else if (c < 20) {
        int aj = atom_j[bt];
        v = (aj != 0) ? emb[aj * NF + (c - 10)] : 0.0f;
    } else {
        int ai = atom_i[bt];
        float d = dist[bt];
        float ctr = (float)(c - 19) * 0.7f;
        float diff = ctr - d;
        v = (ai != 0) ? fexp(-diff * diff) : 0.0f;
    }
    feat[gid] = v;
}

// Kernel 2: GRU recurrence. Block = 128 threads (2 waves) = ONE batch element
// -> grid 2048 blocks = 4096 waves = 4 waves/SIMD (R7 evidence: at 2
// waves/SIMD the per-step chain barrier->ds_read->fma->shfl->trans->barrier
// is exposed; VALUBusy fell 79->70% as issue shrank).
// Hidden unit k is computed by 4 lanes: quarter q = wave*2 + half; each does
// 8 hh j-terms (4 pk-FMA/gate, zero-padded past j=29) and 3 ih d-terms
// (zero-padded past d=9). Reduce: shfl_xor(32) intra-wave, then one float4
// LDS partial exchange cross-wave. Gates/trans redundant in all quarters so
// h stays in a register everywhere.
//
// amdgpu_waves_per_eu(4,4): occupancy ceiling = what the grid supplies, so
// the scheduler's pressure target is 128 regs and weights stay arch-resident
// (R3-R6: without a tight ceiling LLVM shrinks VGPRs for unreachable 8-wave
// occupancy and AGPR-bounces the weights every step: 926->768us when fixed).
__attribute__((amdgpu_waves_per_eu(4, 4)))
__global__ void __launch_bounds__(128)
gru_kernel(const float* __restrict__ feat,
           const float* __restrict__ W_ih,   // [90,10]
           const float* __restrict__ W_hh,   // [90,30]
           const float* __restrict__ b_ih,   // [90]
           const float* __restrict__ b_hh,   // [90]
           const float* __restrict__ W_out,  // [1,30]
           const float* __restrict__ b_out,  // [1]
           float* __restrict__ out) {
    // h double buffer: 32 floats/buffer; slots 30,31 are zero pads (written
    // once, never touched again) so q3's second b128 read multiplies 0.
    __shared__ __align__(16) float hbuf[2][32];
    // Cross-wave partial sums: [wave][half][unit] = {ar, az, ai, ah}
    __shared__ __align__(16) float4 part[2][2][32];

    const int tid  = threadIdx.x;
    const int w    = tid >> 6;         // wave in block
    const int lane = tid & 63;
    const int p    = lane >> 5;        // half within wave
    const int k    = lane & 31;        // hidden unit
    const int q    = w * 2 + p;        // quarter of the reduction
    const bool active = (k < HID);
    const int kk = active ? k : (HID - 1);
    const int b = blockIdx.x;

    // hh weights: 4 j-pairs per gate, j = q*8 .. q*8+7 (>=30 -> 0)
    v2f whh_r[4], whh_z[4], whh_n[4];
#pragma unroll
    for (int jj = 0; jj < 4; ++jj) {
        int j0 = q * 8 + 2 * jj, j1 = j0 + 1;
        float r0 = (j0 < HID) ? W_hh[(0 * HID + kk) * HID + j0] : 0.0f;
        float z0 = (j0 < HID) ? W_hh[(1 * HID + kk) * HID + j0] : 0.0f;
        float n0 = (j0 < HID) ? W_hh[(2 * HID + kk) * HID + j0] : 0.0f;
        float r1 = (j1 < HID) ? W_hh[(0 * HID + kk) * HID + j1] : 0.0f;
        float z1 = (j1 < HID) ? W_hh[(1 * HID + kk) * HID + j1] : 0.0f;
        float n1 = (j1 < HID) ? W_hh[(2 * HID + kk) * HID + j1] : 0.0f;
        whh_r[jj] = (v2f){r0, r1};
        whh_z[jj] = (v2f){z0, z1};
        whh_n[jj] = (v2f){n0, n1};
    }
    // ih weights: 3 d-terms, d = q*3 .. q*3+2 (>=10 -> weight 0, addr clamped)
    float wih_r[3], wih_z[3], wih_n[3];
    int dclamp[3];
#pragma unroll
    for (int dd = 0; dd < 3; ++dd) {
        int d = q * 3 + dd;
        bool real = (d < NF);
        int dm = real ? d : (NF - 1);
        dclamp[dd] = dm;
        wih_r[dd] = real ? W_ih[(0 * HID + kk) * NF + d] : 0.0f;
        wih_z[dd] = real ? W_ih[(1 * HID + kk) * NF + d] : 0.0f;
        wih_n[dd] = real ? W_ih[(2 * HID + kk) * NF + d] : 0.0f;
    }
    // Biases: must appear exactly once in the 4-quarter sum -> only q==0
    // (tid<32) seeds them. n-gate biases stay split (n = tanh(ai + r*ah)).
    const bool seed = (tid < 32);
    const float bini_r = seed ? b_ih[0 * HID + kk] + b_hh[0 * HID + kk] : 0.0f;
    const float bini_z = seed ? b_ih[1 * HID + kk] + b_hh[1 * HID + kk] : 0.0f;
    const float bini_i = seed ? b_ih[2 * HID + kk] : 0.0f;
    const float bini_h = seed ? b_hh[2 * HID + kk] : 0.0f;

    const float* xp = feat + (long)b * FEAT_PER_B;
    const float* xpd[3];
#pragma unroll
    for (int dd = 0; dd < 3; ++dd) xpd[dd] = xp + (long)dclamp[dd] * S3T;

    // Hoisted LDS pointers for the cross-wave exchange
    float4* mypart = &part[w][p][0];
    const float4* opart = &part[1 - w][0][0];  // other wave, half 0

    if (tid < 32) { hbuf[0][tid] = 0.0f; hbuf[1][tid] = 0.0f; }
    __syncthreads();

    float h = 0.0f;
    float xc[3];
#pragma unroll
    for (int dd = 0; dd < 3; ++dd) xc[dd] = xpd[dd][0];

#pragma unroll 2
    for (int s = 0; s < S3T; ++s) {
        const float* rb = hbuf[s & 1];
        float* wb = hbuf[(s + 1) & 1];

        // Prefetch next step's x
        float xn[3];
        const int sn = (s + 1 < S3T) ? (s + 1) : s;
#pragma unroll
        for (int dd = 0; dd < 3; ++dd) xn[dd] = xpd[dd][sn];

        // my quarter's 8 h values: 2 x ds_read_b128 (broadcast across lanes)
        const float4* hv = (const float4*)&rb[q * 8];
        float4 q0 = hv[0], q1 = hv[1];
        v2f hj2[4];
        hj2[0] = (v2f){q0.x, q0.y}; hj2[1] = (v2f){q0.z, q0.w};
        hj2[2] = (v2f){q1.x, q1.y}; hj2[3] = (v2f){q1.z, q1.w};

        v2f a_r = (v2f){bini_r, 0.0f};
        v2f a_z = (v2f){bini_z, 0.0f};
        v2f a_h = (v2f){bini_h, 0.0f};
#pragma unroll
        for (int jj = 0; jj < 4; ++jj) {
            a_r += whh_r[jj] * hj2[jj];
            a_z += whh_z[jj] * hj2[jj];
            a_h += whh_n[jj] * hj2[jj];
        }
        float ar = a_r.x + a_r.y;
        float az = a_z.x + a_z.y;
        float ah = a_h.x + a_h.y;
        float ai = bini_i;
#pragma unroll
        for (int dd = 0; dd < 3; ++dd) {
            ar += wih_r[dd] * xc[dd];
            az += wih_z[dd] * xc[dd];
            ai += wih_n[dd] * xc[dd];
        }
        // intra-wave: sum the two quarters held by this wave
        ar += __shfl_xor(ar, 32, 64);
        az += __shfl_xor(az, 32, 64);
        ai += __shfl_xor(ai, 32, 64);
        ah += __shfl_xor(ah, 32, 64);

        // cross-wave exchange (all lanes write their own slot; read half 0
        // of the other wave — post-shfl both halves hold the wave sum)
        mypart[k] = make_float4(ar, az, ai, ah);
        __syncthreads();
        float4 o = opart[k];
        ar += o.x; az += o.y; ai += o.z; ah += o.w;

        // gates + h update, redundant in all 4 quarters (h stays in-register)
        float rg = sigmoid_(ar);
        float zg = sigmoid_(az);
        float ng = tanh_(ai + rg * ah);
        h = ng + zg * (h - ng);  // (1-z)*n + z*h

        if (tid < HID) wb[tid] = h;  // w0,p0,k<30 writes the canonical h
        __syncthreads();  // h visible before next step's reads; also keeps
                          // this step's rb/part reads ordered vs reuse

#pragma unroll
        for (int dd = 0; dd < 3; ++dd) xc[dd] = xn[dd];
    }

    // out[b] = relu(h . W_out + b_out) — wave 0, half 0 lanes hold h[k]
    if (w == 0) {
        float v = (lane < HID) ? h * W_out[lane] : 0.0f;
#pragma unroll
        for (int off = 32; off; off >>= 1) v += __shfl_xor(v, off, 64);
        if (lane == 0) {
            float o2 = v + b_out[0];
            out[b] = o2 > 0.0f ? o2 : 0.0f;
        }
    }
}

extern "C" void kernel_launch(void* const* d_in, const int* in_sizes, int n_in,
                              void* d_out, int out_size, void* d_ws, size_t ws_size,
                              hipStream_t stream) {
    const int* atom_i   = (const int*)d_in[0];
    const int* atom_j   = (const int*)d_in[1];
    const float* dist   = (const float*)d_in[2];
    const float* emb    = (const float*)d_in[3];
    const float* W_ih   = (const float*)d_in[4];
    const float* W_hh   = (const float*)d_in[5];
    const float* b_ih   = (const float*)d_in[6];
    const float* b_hh   = (const float*)d_in[7];
    const float* W_out  = (const float*)d_in[8];
    const float* b_out  = (const float*)d_in[9];
    float* out = (float*)d_out;
    float* feat = (float*)d_ws;

    const int total = BATCH * FEAT_PER_B;
    const int threads = 256;
    const int blocks = (total + threads - 1) / threads;
    feat_kernel<<<blocks, threads, 0, stream>>>(atom_i, atom_j, dist, emb, feat);
    gru_kernel<<<BATCH, 128, 0, stream>>>(feat, W_ih, W_hh, b_ih, b_hh,
                                          W_out, b_out, out);
}

// Round 9
// 680.251 us; speedup vs baseline: 1.5615x; 1.5615x over previous
//
#include <hip/hip_runtime.h>

// Problem constants (from reference)
#define BATCH 2048
#define T 512
#define NF 10
#define HID 30
#define S3T 1536          // 3*T sequence length after reshape/transpose
#define FEAT_PER_B 15360  // T*30 floats per batch element
// Workspace: BATCH * FEAT_PER_B * 4 = 125,829,120 bytes (fp32 feat)

typedef float v2f __attribute__((ext_vector_type(2)));  // -> v_pk_fma_f32

__device__ __forceinline__ float fexp(float x) {
    return __builtin_amdgcn_exp2f(x * 1.44269504088896f);  // v_exp_f32
}
__device__ __forceinline__ float frcp(float x) {
    return __builtin_amdgcn_rcpf(x);                        // v_rcp_f32
}
__device__ __forceinline__ float sigmoid_(float x) {
    return frcp(1.0f + fexp(-x));
}
__device__ __forceinline__ float tanh_(float x) {
    return 2.0f * frcp(1.0f + fexp(-2.0f * x)) - 1.0f;
}

// Kernel 1: materialize featflat[b][t*30+c] = concat(e_i, e_j, rbf)
__global__ void feat_kernel(const int* __restrict__ atom_i,
                            const int* __restrict__ atom_j,
                            const float* __restrict__ dist,
                            const float* __restrict__ emb,
                            float* __restrict__ feat) {
    int gid = blockIdx.x * blockDim.x + threadIdx.x;
    const int total = BATCH * FEAT_PER_B;
    if (gid >= total) return;
    int b = gid / FEAT_PER_B;
    int r = gid - b * FEAT_PER_B;
    int t = r / 30;
    int c = r - t * 30;
    int bt = b * T + t;
    float v;
    if (c < 10) {
        int ai = atom_i[bt];
        v = (ai != 0) ? emb[ai * NF + c] : 0.0f;
    } else if (c < 20) {
        int aj = atom_j[bt];
        v = (aj != 0) ? emb[aj * NF + (c - 10)] : 0.0f;
    } else {
        int ai = atom_i[bt];
        float d = dist[bt];
        float ctr = (float)(c - 19) * 0.7f;
        float diff = ctr - d;
        v = (ai != 0) ? fexp(-diff * diff) : 0.0f;
    }
    feat[gid] = v;
}

// Kernel 2: GRU recurrence — FULL-DOT mapping, 2 batches per wave.
// Lane k (k<30) computes the COMPLETE ar/az/ai/ah for hidden unit k of its
// half's batch (lanes 0-31 -> batch 2*blk, lanes 32-61 -> batch 2*blk+1):
// 15 pk-FMA x 3 gates (hh) + 5 pk-FMA x 3 gates (ih, x packed v2f).
// NO cross-lane reduction at all (R8 evidence: communication on the
// recurrence critical path loses; R7's 4 shfl+combine were ~25% of issue).
// One wave instruction serves BOTH batches -> ~110 instr/step for 2 batches
// vs R7's 2x195. Grid 1024 single-wave blocks (1 wave/SIMD): __syncthreads
// in a single-wave block is just a waitcnt (no real barrier), and the 4
// independent 15-deep pk chains + 10-load x prefetch provide in-wave ILP.
//
// amdgpu_waves_per_eu(1,1): pressure target 512 regs -> ~160 live values
// (120 weight regs) stay ARCH-resident. R3-R8 evidence: any tighter ceiling
// makes LLVM shrink to ~52 VGPRs and AGPR-bounce the weights every step.
__attribute__((amdgpu_waves_per_eu(1, 1)))
__global__ void __launch_bounds__(64)
gru_kernel(const float* __restrict__ feat,
           const float* __restrict__ W_ih,   // [90,10]
           const float* __restrict__ W_hh,   // [90,30]
           const float* __restrict__ b_ih,   // [90]
           const float* __restrict__ b_hh,   // [90]
           const float* __restrict__ W_out,  // [1,30]
           const float* __restrict__ b_out,  // [1]
           float* __restrict__ out) {
    // Double-buffered h: [buf][half*32 + k]; slots 30,31 / 62,63 are zero
    // pads (init once, never rewritten) so hj pair 15 is never poison.
    __shared__ __align__(16) float hbuf[2][64];
    const int lane = threadIdx.x;
    const int half = lane >> 5;
    const int k    = lane & 31;
    const bool active = (k < HID);
    const int kk = active ? k : (HID - 1);
    const int b = blockIdx.x * 2 + half;

    // Full-row hh weights: 15 v2f (j-pairs 0..29) per gate. Row byte offset
    // (g*30+kk)*120 is 8B-aligned -> float2 loads are legal.
    v2f whr[15], whz[15], whn[15];
    {
        const float2* Rr = (const float2*)&W_hh[(0 * HID + kk) * HID];
        const float2* Rz = (const float2*)&W_hh[(1 * HID + kk) * HID];
        const float2* Rn = (const float2*)&W_hh[(2 * HID + kk) * HID];
#pragma unroll
        for (int j = 0; j < 15; ++j) {
            float2 tr = Rr[j], tz = Rz[j], tn = Rn[j];
            whr[j] = (v2f){tr.x, tr.y};
            whz[j] = (v2f){tz.x, tz.y};
            whn[j] = (v2f){tn.x, tn.y};
        }
    }
    // Full-row ih weights: 5 v2f per gate (row offset (g*30+kk)*40, 8B-aligned)
    v2f wir[5], wiz[5], win[5];
    {
        const float2* Rr = (const float2*)&W_ih[(0 * HID + kk) * NF];
        const float2* Rz = (const float2*)&W_ih[(1 * HID + kk) * NF];
        const float2* Rn = (const float2*)&W_ih[(2 * HID + kk) * NF];
#pragma unroll
        for (int d = 0; d < 5; ++d) {
            float2 tr = Rr[d], tz = Rz[d], tn = Rn[d];
            wir[d] = (v2f){tr.x, tr.y};
            wiz[d] = (v2f){tz.x, tz.y};
            win[d] = (v2f){tn.x, tn.y};
        }
    }
    // Biases: each lane owns the full sum -> add directly. n-gate stays
    // split: n = tanh((ih_n + b_ih_n) + r * (hh_n + b_hh_n)).
    const float br  = b_ih[0 * HID + kk] + b_hh[0 * HID + kk];
    const float bz  = b_ih[1 * HID + kk] + b_hh[1 * HID + kk];
    const float bin = b_ih[2 * HID + kk];
    const float bhn = b_hh[2 * HID + kk];

    const float* xp = feat + (long)b * FEAT_PER_B;

    hbuf[0][lane] = 0.0f;  // zero both buffers (incl. pads 30,31,62,63)
    hbuf[1][lane] = 0.0f;
    __syncthreads();

    float h = 0.0f;
    // x packed as 5 v2f (d-pairs); addresses wave-uniform per half
    v2f xc[5];
#pragma unroll
    for (int d = 0; d < 5; ++d)
        xc[d] = (v2f){xp[(2 * d) * S3T], xp[(2 * d + 1) * S3T]};

#pragma unroll 2
    for (int s = 0; s < S3T; ++s) {
        const float* rb = hbuf[s & 1];
        float* wb = hbuf[(s + 1) & 1];

        // Prefetch next step's x (10 scalar loads, independent of the chain)
        v2f xn[5];
        const int sn = (s + 1 < S3T) ? (s + 1) : s;
#pragma unroll
        for (int d = 0; d < 5; ++d)
            xn[d] = (v2f){xp[(2 * d) * S3T + sn], xp[(2 * d + 1) * S3T + sn]};

        // My half's h: 8 x ds_read_b128 = 32 floats (pairs 0..14 used, pad=0)
        const float4* hv = (const float4*)&rb[half * 32];
        v2f hj[16];
#pragma unroll
        for (int q = 0; q < 8; ++q) {
            float4 t = hv[q];
            hj[2 * q]     = (v2f){t.x, t.y};
            hj[2 * q + 1] = (v2f){t.z, t.w};
        }

        // Complete dots per lane: 4 independent 15/5-deep pk chains
        v2f ar2 = (v2f){br, 0.0f};
        v2f az2 = (v2f){bz, 0.0f};
        v2f ah2 = (v2f){bhn, 0.0f};
        v2f ai2 = (v2f){bin, 0.0f};
#pragma unroll
        for (int j = 0; j < 15; ++j) {
            ar2 += whr[j] * hj[j];
            az2 += whz[j] * hj[j];
            ah2 += whn[j] * hj[j];
        }
#pragma unroll
        for (int d = 0; d < 5; ++d) {
            ar2 += wir[d] * xc[d];
            az2 += wiz[d] * xc[d];
            ai2 += win[d] * xc[d];
        }
        float ar = ar2.x + ar2.y;
        float az = az2.x + az2.y;
        float ah = ah2.x + ah2.y;
        float ai = ai2.x + ai2.y;

        float rg = sigmoid_(ar);
        float zg = sigmoid_(az);
        float ng = tanh_(ai + rg * ah);
        h = ng + zg * (h - ng);  // (1-z)*n + z*h

        if (active) wb[half * 32 + k] = h;
        __syncthreads();  // single-wave block: compiles to a cheap waitcnt

#pragma unroll
        for (int d = 0; d < 5; ++d) xc[d] = xn[d];
    }

    // out[b] = relu(h . W_out + b_out), reduced within each 32-lane half
    float v = active ? h * W_out[kk] : 0.0f;
#pragma unroll
    for (int off = 16; off; off >>= 1) v += __shfl_xor(v, off, 32);
    if (k == 0) {
        float o = v + b_out[0];
        out[b] = o > 0.0f ? o : 0.0f;
    }
}

extern "C" void kernel_launch(void* const* d_in, const int* in_sizes, int n_in,
                              void* d_out, int out_size, void* d_ws, size_t ws_size,
                              hipStream_t stream) {
    const int* atom_i   = (const int*)d_in[0];
    const int* atom_j   = (const int*)d_in[1];
    const float* dist   = (const float*)d_in[2];
    const float* emb    = (const float*)d_in[3];
    const float* W_ih   = (const float*)d_in[4];
    const float* W_hh   = (const float*)d_in[5];
    const float* b_ih   = (const float*)d_in[6];
    const float* b_hh   = (const float*)d_in[7];
    const float* W_out  = (const float*)d_in[8];
    const float* b_out  = (const float*)d_in[9];
    float* out = (float*)d_out;
    float* feat = (float*)d_ws;

    const int total = BATCH * FEAT_PER_B;
    const int threads = 256;
    const int blocks = (total + threads - 1) / threads;
    feat_kernel<<<blocks, threads, 0, stream>>>(atom_i, atom_j, dist, emb, feat);
    gru_kernel<<<BATCH / 2, 64, 0, stream>>>(feat, W_ih, W_hh, b_ih, b_hh,
                                             W_out, b_out, out);
}

// Round 10
// 527.375 us; speedup vs baseline: 2.0142x; 1.2899x over previous
//
#include <hip/hip_runtime.h>

// Problem constants (from reference)
#define BATCH 2048
#define T 512
#define NF 10
#define HID 30
#define S3T 1536          // 3*T sequence length after reshape/transpose
#define FEAT_PER_B 15360  // 10*1536 floats per batch element
// Workspace: BATCH * FEAT_PER_B * 4 = 125,829,120 bytes
// Layout: xpair[b][p][s][e] (p<5, s<1536, e<2): x[b][s][2p+e] — one dwordx4
// at (b,p,2*ch) = d-pair (2p,2p+1) for steps 2ch,2ch+1 -> natural v2f pairs.

typedef float v2f __attribute__((ext_vector_type(2)));  // -> v_pk_fma_f32

__device__ __forceinline__ float fexp(float x) {
    return __builtin_amdgcn_exp2f(x * 1.44269504088896f);  // v_exp_f32
}
__device__ __forceinline__ float frcp(float x) {
    return __builtin_amdgcn_rcpf(x);                        // v_rcp_f32
}
__device__ __forceinline__ float sigmoid_(float x) {
    return frcp(1.0f + fexp(-x));
}
__device__ __forceinline__ float tanh_(float x) {
    return 2.0f * frcp(1.0f + fexp(-2.0f * x)) - 1.0f;
}

// Kernel 1: materialize xpair[b][p][s][e] = x[b][s][2p+e]; same per-element
// math as before (e_i / e_j / rbf via t=f/30, c=f%30, f=(2p+e)*1536+s).
// gid-ordered writes stay perfectly coalesced.
__global__ void feat_kernel(const int* __restrict__ atom_i,
                            const int* __restrict__ atom_j,
                            const float* __restrict__ dist,
                            const float* __restrict__ emb,
                            float* __restrict__ xpair) {
    int gid = blockIdx.x * blockDim.x + threadIdx.x;
    const int total = BATCH * FEAT_PER_B;
    if (gid >= total) return;
    int b = gid / FEAT_PER_B;
    int r = gid - b * FEAT_PER_B;
    int p = r / 3072;
    int q = r - p * 3072;
    int s = q >> 1;
    int e = q & 1;
    int f = (2 * p + e) * 1536 + s;   // flat index into featflat_b
    int t = f / 30;
    int c = f - t * 30;
    int bt = b * T + t;
    float v;
    if (c < 10) {
        int ai = atom_i[bt];
        v = (ai != 0) ? emb[ai * NF + c] : 0.0f;
    } else if (c < 20) {
        int aj = atom_j[bt];
        v = (aj != 0) ? emb[aj * NF + (c - 10)] : 0.0f;
    } else {
        int ai = atom_i[bt];
        float dd = dist[bt];
        float ctr = (float)(c - 19) * 0.7f;
        float diff = ctr - dd;
        v = (ai != 0) ? fexp(-diff * diff) : 0.0f;
    }
    xpair[gid] = v;
}

// One GRU step: reads hbuf[PAR], writes hbuf[PAR^1]. XQ = 5 float4 chunk
// regs; IDX selects low/high v2f half (step 2ch / 2ch+1). The trailing
// wavefront-scope fence replaces __syncthreads: single-wave block + in-order
// DS per wave make the barrier unnecessary; the barrier's vmcnt(0) drain was
// putting the x-prefetch LLC/HBM latency on the critical path every step.
#define STEP(PAR, XQ, IDX)                                                   \
    {                                                                        \
        const float4* hv = (const float4*)&hbuf[PAR][half * 32];             \
        v2f hj[16];                                                          \
        _Pragma("unroll")                                                    \
        for (int qq = 0; qq < 8; ++qq) {                                     \
            float4 tq = hv[qq];                                              \
            __builtin_memcpy(&hj[2 * qq], &tq, 16);                          \
        }                                                                    \
        v2f xc[5];                                                           \
        _Pragma("unroll")                                                    \
        for (int pp = 0; pp < 5; ++pp)                                       \
            __builtin_memcpy(&xc[pp], ((const char*)&XQ[pp]) + 8 * (IDX), 8);\
        v2f ar2 = whr[0] * hj[0] + brv;  /* bias folded into first pk_fma */ \
        v2f az2 = whz[0] * hj[0] + bzv;                                      \
        v2f ah2 = whn[0] * hj[0] + bhv;                                      \
        _Pragma("unroll")                                                    \
        for (int j = 1; j < 15; ++j) {                                       \
            ar2 += whr[j] * hj[j];                                           \
            az2 += whz[j] * hj[j];                                           \
            ah2 += whn[j] * hj[j];                                           \
        }                                                                    \
        v2f ai2 = win[0] * xc[0] + biv;                                      \
        _Pragma("unroll")                                                    \
        for (int d2 = 1; d2 < 5; ++d2) ai2 += win[d2] * xc[d2];              \
        _Pragma("unroll")                                                    \
        for (int d2 = 0; d2 < 5; ++d2) {                                     \
            ar2 += wir[d2] * xc[d2];                                         \
            az2 += wiz[d2] * xc[d2];                                         \
        }                                                                    \
        float ar = ar2.x + ar2.y, az = az2.x + az2.y;                        \
        float ah = ah2.x + ah2.y, ai = ai2.x + ai2.y;                        \
        float rg = sigmoid_(ar), zg = sigmoid_(az);                          \
        float ng = tanh_(ai + rg * ah);                                      \
        h = ng + zg * (h - ng);                                              \
        hbuf[(PAR) ^ 1][half * 32 + k] = h;                                  \
        __builtin_amdgcn_fence(__ATOMIC_ACQ_REL, "wavefront");               \
    }

// Kernel 2: GRU recurrence — full-dot mapping (R9 winner), 2 batches/wave.
// Lane k (k<30) computes complete gates for unit k of its half's batch.
// amdgpu_waves_per_eu(1,1): pressure target 512 regs -> ~230 live values
// stay ARCH-resident (R3-R8: tighter ceilings AGPR-bounce the weights).
__attribute__((amdgpu_waves_per_eu(1, 1)))
__global__ void __launch_bounds__(64)
gru_kernel(const float* __restrict__ xpair,
           const float* __restrict__ W_ih,   // [90,10]
           const float* __restrict__ W_hh,   // [90,30]
           const float* __restrict__ b_ih,   // [90]
           const float* __restrict__ b_hh,   // [90]
           const float* __restrict__ W_out,  // [1,30]
           const float* __restrict__ b_out,  // [1]
           float* __restrict__ out) {
    // Double-buffered h: [buf][half*32 + k]; slots 30,31/62,63 are written by
    // the inactive lanes (k=30,31) but never read (hj[15] unused).
    __shared__ __align__(16) float hbuf[2][64];
    const int lane = threadIdx.x;
    const int half = lane >> 5;
    const int k    = lane & 31;
    const bool active = (k < HID);
    const int kk = active ? k : (HID - 1);
    const int b = blockIdx.x * 2 + half;

    // Full-row hh weights: 15 v2f (j-pairs) per gate; rows 8B-aligned.
    v2f whr[15], whz[15], whn[15];
    {
        const float2* Rr = (const float2*)&W_hh[(0 * HID + kk) * HID];
        const float2* Rz = (const float2*)&W_hh[(1 * HID + kk) * HID];
        const float2* Rn = (const float2*)&W_hh[(2 * HID + kk) * HID];
#pragma unroll
        for (int j = 0; j < 15; ++j) {
            float2 tr = Rr[j], tz = Rz[j], tn = Rn[j];
            whr[j] = (v2f){tr.x, tr.y};
            whz[j] = (v2f){tz.x, tz.y};
            whn[j] = (v2f){tn.x, tn.y};
        }
    }
    // Full-row ih weights: 5 v2f per gate (d-pairs match xpair layout).
    v2f wir[5], wiz[5], win[5];
    {
        const float2* Rr = (const float2*)&W_ih[(0 * HID + kk) * NF];
        const float2* Rz = (const float2*)&W_ih[(1 * HID + kk) * NF];
        const float2* Rn = (const float2*)&W_ih[(2 * HID + kk) * NF];
#pragma unroll
        for (int d = 0; d < 5; ++d) {
            float2 tr = Rr[d], tz = Rz[d], tn = Rn[d];
            wir[d] = (v2f){tr.x, tr.y};
            wiz[d] = (v2f){tz.x, tz.y};
            win[d] = (v2f){tn.x, tn.y};
        }
    }
    // Biases as v2f for the fma-init trick (added exactly once per dot).
    const v2f brv = (v2f){b_ih[0 * HID + kk] + b_hh[0 * HID + kk], 0.0f};
    const v2f bzv = (v2f){b_ih[1 * HID + kk] + b_hh[1 * HID + kk], 0.0f};
    const v2f biv = (v2f){b_ih[2 * HID + kk], 0.0f};  // n biases stay split:
    const v2f bhv = (v2f){b_hh[2 * HID + kk], 0.0f};  // n = tanh(ai + r*ah)

    // 5 chunk base pointers: xa[p][ch] = d-pair (2p,2p+1) for steps 2ch,2ch+1
    const float* xb = xpair + (long)b * FEAT_PER_B;
    const float4* xa[5];
#pragma unroll
    for (int p = 0; p < 5; ++p) xa[p] = (const float4*)(xb + p * 3072);

    hbuf[0][lane] = 0.0f;
    hbuf[1][lane] = 0.0f;
    __builtin_amdgcn_fence(__ATOMIC_ACQ_REL, "wavefront");

    float h = 0.0f;
    float4 xq0[5], xq1[5];
#pragma unroll
    for (int p = 0; p < 5; ++p) xq0[p] = xa[p][0];

    // 768 chunks of 2 steps, processed in pairs for compile-time buffer parity
    for (int c2 = 0; c2 < 768; c2 += 2) {
        // prefetch chunk c2+1 (always valid: c2+1 <= 767)
#pragma unroll
        for (int p = 0; p < 5; ++p) xq1[p] = xa[p][c2 + 1];
        STEP(0, xq0, 0);   // step 2*c2
        STEP(1, xq0, 1);   // step 2*c2+1
        const int cn = (c2 + 2 < 768) ? (c2 + 2) : 767;  // clamp final OOB
#pragma unroll
        for (int p = 0; p < 5; ++p) xq0[p] = xa[p][cn];
        STEP(0, xq1, 0);   // step 2*c2+2
        STEP(1, xq1, 1);   // step 2*c2+3
    }

    // out[b] = relu(h . W_out + b_out), reduced within each 32-lane half
    float v = active ? h * W_out[kk] : 0.0f;
#pragma unroll
    for (int off = 16; off; off >>= 1) v += __shfl_xor(v, off, 32);
    if (k == 0) {
        float o = v + b_out[0];
        out[b] = o > 0.0f ? o : 0.0f;
    }
}

extern "C" void kernel_launch(void* const* d_in, const int* in_sizes, int n_in,
                              void* d_out, int out_size, void* d_ws, size_t ws_size,
                              hipStream_t stream) {
    const int* atom_i   = (const int*)d_in[0];
    const int* atom_j   = (const int*)d_in[1];
    const float* dist   = (const float*)d_in[2];
    const float* emb    = (const float*)d_in[3];
    const float* W_ih   = (const float*)d_in[4];
    const float* W_hh   = (const float*)d_in[5];
    const float* b_ih   = (const float*)d_in[6];
    const float* b_hh   = (const float*)d_in[7];
    const float* W_out  = (const float*)d_in[8];
    const float* b_out  = (const float*)d_in[9];
    float* out = (float*)d_out;
    float* xpair = (float*)d_ws;

    const int total = BATCH * FEAT_PER_B;
    const int threads = 256;
    const int blocks = (total + threads - 1) / threads;
    feat_kernel<<<blocks, threads, 0, stream>>>(atom_i, atom_j, dist, emb, xpair);
    gru_kernel<<<BATCH / 2, 64, 0, stream>>>(xpair, W_ih, W_hh, b_ih, b_hh,
                                             W_out, b_out, out);
}